// Round 14
// baseline (516.837 us; speedup 1.0000x reference)
//
#include <hip/hip_runtime.h>

#define NN 100000
#define D 128
#define CHUNK 4096
#define BCSTRIDE 392
#define AGG_BLOCKS 1536

typedef __attribute__((ext_vector_type(8))) short short8;
typedef __attribute__((ext_vector_type(8))) unsigned short ushort8;
typedef __attribute__((ext_vector_type(4))) float f32x4;

__device__ __forceinline__ float4 ld4(const float* p) { return *(const float4*)p; }

__device__ __forceinline__ unsigned short f2bf(float f) {
    unsigned int u = __float_as_uint(f);
    unsigned int r = u + 0x7fffu + ((u >> 16) & 1u);   // RNE
    return (unsigned short)(r >> 16);
}
__device__ __forceinline__ float bf2f(unsigned short h) {
    return __uint_as_float(((unsigned int)h) << 16);
}

// ---------------- W prepack: fragment-ordered hi/lo bf16 ----------------
__global__ __launch_bounds__(256) void prepack_w(
    const float* __restrict__ W, unsigned short* __restrict__ hi,
    unsigned short* __restrict__ lo)
{
    const int t = blockIdx.x * 256 + threadIdx.x;
    if (t >= D * D) return;
    const int j  = t & 7;
    const int L  = (t >> 3) & 63;
    const int ks = (t >> 9) & 3;
    const int nt = t >> 11;
    const float v = W[(ks * 32 + (L >> 4) * 8 + j) * D + nt * 16 + (L & 15)];
    const unsigned short h = f2bf(v);
    hi[t] = h;
    lo[t] = f2bf(v - bf2f(h));
}

// ---------------- emb prepack: packed bf16 pairs, h_hi-compatible layout ----------------
__global__ __launch_bounds__(256) void prepack_emb(
    const float* __restrict__ emb, unsigned int* __restrict__ embp)
{
    const int i = blockIdx.x * 256 + threadIdx.x;
    if (i >= 100 * 64) return;
    const float a = emb[i * 2];
    const float b = emb[i * 2 + 1];
    embp[i] = (unsigned int)f2bf(a) | ((unsigned int)f2bf(b) << 16);
}

// ---------------- input GEMM: h(split) = x @ Win + b_in ----------------
__global__ __launch_bounds__(256) void gemm_in(
    const float* __restrict__ A1,
    const unsigned short* __restrict__ Whi, const unsigned short* __restrict__ Wlo,
    const float* __restrict__ bias,
    unsigned short* __restrict__ out_hi, unsigned short* __restrict__ out_lo, int N)
{
    __shared__ unsigned int uT[64 * 132];
    const int t  = threadIdx.x;
    const int wv = t >> 6;
    const int L  = t & 63;
    const int lr = L & 15;
    const int q  = L >> 4;
    const int rbase = wv * 16;
    const int row = blockIdx.x * 64 + rbase + lr;

    short8 ahi[4], alo[4];
    #pragma unroll
    for (int ks = 0; ks < 4; ++ks) {
        float v[8];
        if (row < N) {
            const int off = row * D + ks * 32 + q * 8;
            const float4 x0 = ld4(&A1[off]), x1 = ld4(&A1[off + 4]);
            v[0] = x0.x; v[1] = x0.y; v[2] = x0.z; v[3] = x0.w;
            v[4] = x1.x; v[5] = x1.y; v[6] = x1.z; v[7] = x1.w;
        } else {
            #pragma unroll
            for (int j = 0; j < 8; ++j) v[j] = 0.f;
        }
        #pragma unroll
        for (int j = 0; j < 8; ++j) {
            const unsigned short h = f2bf(v[j]);
            ahi[ks][j] = (short)h;
            alo[ks][j] = (short)f2bf(v[j] - bf2f(h));
        }
    }

    f32x4 acc[8];
    #pragma unroll
    for (int nt = 0; nt < 8; ++nt) acc[nt] = (f32x4){0.f, 0.f, 0.f, 0.f};

    #pragma unroll
    for (int ks = 0; ks < 4; ++ks)
        #pragma unroll
        for (int nt = 0; nt < 8; ++nt) {
            const int base = ((nt * 4 + ks) * 64 + L) * 8;
            const short8 bhi = *(const short8*)&Whi[base];
            const short8 blo = *(const short8*)&Wlo[base];
            acc[nt] = __builtin_amdgcn_mfma_f32_16x16x32_bf16(alo[ks], bhi, acc[nt], 0, 0, 0);
            acc[nt] = __builtin_amdgcn_mfma_f32_16x16x32_bf16(ahi[ks], blo, acc[nt], 0, 0, 0);
            acc[nt] = __builtin_amdgcn_mfma_f32_16x16x32_bf16(ahi[ks], bhi, acc[nt], 0, 0, 0);
        }

    #pragma unroll
    for (int nt = 0; nt < 8; ++nt) {
        const float b = bias[nt * 16 + lr];
        #pragma unroll
        for (int r = 0; r < 4; ++r) {
            const int rloc = rbase + q * 4 + r;
            uT[rloc * 132 + nt * 16 + lr] = __float_as_uint(acc[nt][r] + b);
        }
    }
    __syncthreads();
    if (row < N) {
        #pragma unroll
        for (int ks = 0; ks < 4; ++ks) {
            const unsigned int* p = &uT[(rbase + lr) * 132 + ks * 32 + q * 8];
            const int off = row * D + ks * 32 + q * 8;
            ushort8 oh, ol;
            #pragma unroll
            for (int j = 0; j < 8; ++j) {
                const float o = __uint_as_float(p[j]);
                const unsigned short h = f2bf(o);
                oh[j] = h;
                ol[j] = f2bf(o - bf2f(h));
            }
            *(ushort8*)&out_hi[off] = oh;
            *(ushort8*)&out_lo[off] = ol;
        }
    }
}

// ---------------- fused GINE MLP (unchanged from R9) ----------------
template<bool LAST>
__global__ __launch_bounds__(256) void mlp_fused(
    const float* __restrict__ agg,
    const unsigned short* __restrict__ h_hi, const unsigned short* __restrict__ h_lo,
    const unsigned short* __restrict__ W1hi, const unsigned short* __restrict__ W1lo,
    const float* __restrict__ b1,
    const unsigned short* __restrict__ W2hi, const unsigned short* __restrict__ W2lo,
    const float* __restrict__ b2,
    unsigned short* __restrict__ out_hi, unsigned short* __restrict__ out_lo,
    float* __restrict__ out_f, int N)
{
    __shared__ unsigned int uT[64 * 132];
    const int t  = threadIdx.x;
    const int wv = t >> 6;
    const int L  = t & 63;
    const int lr = L & 15;
    const int q  = L >> 4;
    const int rbase = wv * 16;
    const int row = blockIdx.x * 64 + rbase + lr;

    ushort8 hh[4], ll[4];
    short8 ahi[4], alo[4];
    #pragma unroll
    for (int ks = 0; ks < 4; ++ks) {
        float v[8];
        if (row < N) {
            const int off = row * D + ks * 32 + q * 8;
            const float4 x0 = ld4(&agg[off]), x1 = ld4(&agg[off + 4]);
            hh[ks] = *(const ushort8*)&h_hi[off];
            ll[ks] = *(const ushort8*)&h_lo[off];
            v[0] = x0.x; v[1] = x0.y; v[2] = x0.z; v[3] = x0.w;
            v[4] = x1.x; v[5] = x1.y; v[6] = x1.z; v[7] = x1.w;
        } else {
            hh[ks] = (ushort8)0; ll[ks] = (ushort8)0;
            #pragma unroll
            for (int j = 0; j < 8; ++j) v[j] = 0.f;
        }
        #pragma unroll
        for (int j = 0; j < 8; ++j) {
            v[j] += bf2f(hh[ks][j]) + bf2f(ll[ks][j]);
            const unsigned short h = f2bf(v[j]);
            ahi[ks][j] = (short)h;
            alo[ks][j] = (short)f2bf(v[j] - bf2f(h));
        }
    }

    f32x4 acc[8];
    #pragma unroll
    for (int nt = 0; nt < 8; ++nt) acc[nt] = (f32x4){0.f, 0.f, 0.f, 0.f};

    #pragma unroll
    for (int ks = 0; ks < 4; ++ks)
        #pragma unroll
        for (int nt = 0; nt < 8; ++nt) {
            const int base = ((nt * 4 + ks) * 64 + L) * 8;
            const short8 bhi = *(const short8*)&W1hi[base];
            const short8 blo = *(const short8*)&W1lo[base];
            acc[nt] = __builtin_amdgcn_mfma_f32_16x16x32_bf16(alo[ks], bhi, acc[nt], 0, 0, 0);
            acc[nt] = __builtin_amdgcn_mfma_f32_16x16x32_bf16(ahi[ks], blo, acc[nt], 0, 0, 0);
            acc[nt] = __builtin_amdgcn_mfma_f32_16x16x32_bf16(ahi[ks], bhi, acc[nt], 0, 0, 0);
        }

    #pragma unroll
    for (int nt = 0; nt < 8; ++nt) {
        const float b = b1[nt * 16 + lr];
        #pragma unroll
        for (int r = 0; r < 4; ++r) {
            const int rloc = rbase + q * 4 + r;
            const float o = fmaxf(acc[nt][r] + b, 0.f);
            const unsigned int hi = f2bf(o);
            const unsigned int lo = f2bf(o - bf2f((unsigned short)hi));
            uT[rloc * 132 + nt * 16 + lr] = (hi << 16) | lo;
        }
    }
    __syncthreads();

    short8 uhi[4], ulo[4];
    #pragma unroll
    for (int ks = 0; ks < 4; ++ks) {
        const unsigned int* p = &uT[(rbase + lr) * 132 + ks * 32 + q * 8];
        #pragma unroll
        for (int j = 0; j < 8; ++j) {
            const unsigned int v = p[j];
            uhi[ks][j] = (short)(v >> 16);
            ulo[ks][j] = (short)(v & 0xffffu);
        }
    }

    f32x4 acc2[8];
    #pragma unroll
    for (int nt = 0; nt < 8; ++nt) acc2[nt] = (f32x4){0.f, 0.f, 0.f, 0.f};

    #pragma unroll
    for (int ks = 0; ks < 4; ++ks)
        #pragma unroll
        for (int nt = 0; nt < 8; ++nt) {
            const int base = ((nt * 4 + ks) * 64 + L) * 8;
            const short8 bhi = *(const short8*)&W2hi[base];
            const short8 blo = *(const short8*)&W2lo[base];
            acc2[nt] = __builtin_amdgcn_mfma_f32_16x16x32_bf16(ulo[ks], bhi, acc2[nt], 0, 0, 0);
            acc2[nt] = __builtin_amdgcn_mfma_f32_16x16x32_bf16(uhi[ks], blo, acc2[nt], 0, 0, 0);
            acc2[nt] = __builtin_amdgcn_mfma_f32_16x16x32_bf16(uhi[ks], bhi, acc2[nt], 0, 0, 0);
        }
    __syncthreads();

    #pragma unroll
    for (int nt = 0; nt < 8; ++nt) {
        const float b = b2[nt * 16 + lr];
        #pragma unroll
        for (int r = 0; r < 4; ++r) {
            const int rloc = rbase + q * 4 + r;
            uT[rloc * 132 + nt * 16 + lr] = __float_as_uint(acc2[nt][r] + b);
        }
    }
    __syncthreads();

    if (row < N) {
        #pragma unroll
        for (int ks = 0; ks < 4; ++ks) {
            const unsigned int* p = &uT[(rbase + lr) * 132 + ks * 32 + q * 8];
            const int off = row * D + ks * 32 + q * 8;
            float o[8];
            #pragma unroll
            for (int j = 0; j < 8; ++j)
                o[j] = fmaxf(__uint_as_float(p[j]) + bf2f(hh[ks][j]) + bf2f(ll[ks][j]), 0.f);
            if (LAST) {
                *(float4*)&out_f[off]     = make_float4(o[0], o[1], o[2], o[3]);
                *(float4*)&out_f[off + 4] = make_float4(o[4], o[5], o[6], o[7]);
            } else {
                ushort8 oh, ol;
                #pragma unroll
                for (int j = 0; j < 8; ++j) {
                    const unsigned short h = f2bf(o[j]);
                    oh[j] = h;
                    ol[j] = f2bf(o[j] - bf2f(h));
                }
                *(ushort8*)&out_hi[off] = oh;
                *(ushort8*)&out_lo[off] = ol;
            }
        }
    }
}

// ---------------- binned CSR build ----------------
__global__ __launch_bounds__(256) void bin_count(
    const int* __restrict__ dst, int* __restrict__ blkcnt,
    int* __restrict__ binTotal, int E, int nbins)
{
    __shared__ int hist[512];
    const int t = threadIdx.x;
    const int i = blockIdx.x;
    for (int k = t; k < nbins; k += 256) hist[k] = 0;
    __syncthreads();
    const int e0 = i * CHUNK;
    const int e1 = min(E, e0 + CHUNK);
    for (int e = e0 + t; e < e1; e += 256) atomicAdd(&hist[dst[e] >> 8], 1);
    __syncthreads();
    for (int k = t; k < nbins; k += 256) {
        const int c = hist[k];
        blkcnt[i * BCSTRIDE + k] = c;
        if (c) atomicAdd(&binTotal[k], c);
    }
}

__global__ __launch_bounds__(512) void bin_scan(
    const int* __restrict__ binTotal, int* __restrict__ binStart,
    int* __restrict__ binCursor, int nbins)
{
    __shared__ int s[512];
    const int t = threadIdx.x;
    const int v = (t < nbins) ? binTotal[t] : 0;
    s[t] = v;
    __syncthreads();
    for (int off = 1; off < 512; off <<= 1) {
        const int x = (t >= off) ? s[t - off] : 0;
        __syncthreads();
        s[t] += x;
        __syncthreads();
    }
    if (t < nbins) { binStart[t] = s[t] - v; binCursor[t] = s[t] - v; }
    if (t == 0)    binStart[nbins] = s[511];
}

__global__ __launch_bounds__(256) void bin_scatter(
    const int* __restrict__ src, const int* __restrict__ dst,
    const int* __restrict__ attr, const int* __restrict__ blkcnt,
    int* __restrict__ binCursor, int2* __restrict__ binned, int E, int nbins)
{
    __shared__ int cur[512];
    const int t = threadIdx.x;
    const int i = blockIdx.x;
    for (int k = t; k < nbins; k += 256) {
        const int c = blkcnt[i * BCSTRIDE + k];
        if (c) cur[k] = atomicAdd(&binCursor[k], c);
    }
    __syncthreads();
    const int e0 = i * CHUNK;
    const int e1 = min(E, e0 + CHUNK);
    for (int e = e0 + t; e < e1; e += 256) {
        const int d = dst[e];
        const int p = atomicAdd(&cur[d >> 8], 1);
        binned[p] = make_int2(src[e] | (attr[e] << 20), d);
    }
}

__global__ __launch_bounds__(256) void bin_build(
    const int2* __restrict__ binned, const int* __restrict__ binStart,
    int* __restrict__ rowptr, int* __restrict__ epack, int N)
{
    __shared__ int hist[256];
    __shared__ int scn[256];
    __shared__ int curn[256];
    const int t = threadIdx.x;
    const int b = blockIdx.x;
    hist[t] = 0;
    __syncthreads();
    const int ebeg = binStart[b];
    const int eend = binStart[b + 1];
    for (int e = ebeg + t; e < eend; e += 256) atomicAdd(&hist[binned[e].y & 255], 1);
    __syncthreads();
    scn[t] = hist[t];
    __syncthreads();
    for (int off = 1; off < 256; off <<= 1) {
        const int x = (t >= off) ? scn[t - off] : 0;
        __syncthreads();
        scn[t] += x;
        __syncthreads();
    }
    const int node = b * 256 + t;
    if (node < N) rowptr[node] = ebeg + scn[t];
    curn[t] = ebeg + scn[t] - hist[t];
    __syncthreads();
    for (int e = ebeg + t; e < eend; e += 256) {
        const int2 v = binned[e];
        const int p = atomicAdd(&curn[v.y & 255], 1);
        epack[p] = v.x;
    }
}

// ---------------- CSR aggregate: LDS-staged packed emb, node-looping waves ----------------
__global__ __launch_bounds__(256) void aggregate(
    const unsigned int* __restrict__ hu,
    const int* __restrict__ rowptr, const int* __restrict__ epack,
    const unsigned int* __restrict__ embp, float* __restrict__ agg, int N)
{
    __shared__ unsigned int semb[100 * 64];   // 25.6 KB packed bf16 emb table
    const int t = threadIdx.x;
    for (int i = t; i < 100 * 64; i += 256) semb[i] = embp[i];
    __syncthreads();

    const int wv   = t >> 6;
    const int lane = t & 63;

    for (int node = blockIdx.x * 4 + wv; node < N; node += AGG_BLOCKS * 4) {
        int start = (node == 0) ? 0 : rowptr[node - 1];
        int end   = rowptr[node];
        start = __builtin_amdgcn_readfirstlane(start);
        end   = __builtin_amdgcn_readfirstlane(end);

        float ax = 0.f, ay = 0.f;
        int j = start;

        for (; j < end && (j & 3); ++j) {
            const int p0 = __builtin_amdgcn_readfirstlane(epack[j]);
            const unsigned int u0 = hu[(p0 & 0xFFFFF) * 64 + lane];
            const unsigned int v0 = semb[(p0 >> 20) * 64 + lane];
            ax += fmaxf(__uint_as_float(u0 << 16) + __uint_as_float(v0 << 16), 0.f);
            ay += fmaxf(__uint_as_float(u0 & 0xffff0000u) + __uint_as_float(v0 & 0xffff0000u), 0.f);
        }

        for (; j + 7 < end; j += 8) {
            const int4 pk0 = *(const int4*)&epack[j];
            const int4 pk1 = *(const int4*)&epack[j + 4];
            int p[8];
            p[0] = __builtin_amdgcn_readfirstlane(pk0.x);
            p[1] = __builtin_amdgcn_readfirstlane(pk0.y);
            p[2] = __builtin_amdgcn_readfirstlane(pk0.z);
            p[3] = __builtin_amdgcn_readfirstlane(pk0.w);
            p[4] = __builtin_amdgcn_readfirstlane(pk1.x);
            p[5] = __builtin_amdgcn_readfirstlane(pk1.y);
            p[6] = __builtin_amdgcn_readfirstlane(pk1.z);
            p[7] = __builtin_amdgcn_readfirstlane(pk1.w);
            unsigned int u[8], v[8];
            #pragma unroll
            for (int k = 0; k < 8; ++k) u[k] = hu[(p[k] & 0xFFFFF) * 64 + lane];
            #pragma unroll
            for (int k = 0; k < 8; ++k) v[k] = semb[(p[k] >> 20) * 64 + lane];
            #pragma unroll
            for (int k = 0; k < 8; ++k) {
                ax += fmaxf(__uint_as_float(u[k] << 16) + __uint_as_float(v[k] << 16), 0.f);
                ay += fmaxf(__uint_as_float(u[k] & 0xffff0000u) + __uint_as_float(v[k] & 0xffff0000u), 0.f);
            }
        }

        if (j + 3 < end) {
            const int4 pk0 = *(const int4*)&epack[j];
            int p[4];
            p[0] = __builtin_amdgcn_readfirstlane(pk0.x);
            p[1] = __builtin_amdgcn_readfirstlane(pk0.y);
            p[2] = __builtin_amdgcn_readfirstlane(pk0.z);
            p[3] = __builtin_amdgcn_readfirstlane(pk0.w);
            unsigned int u[4], v[4];
            #pragma unroll
            for (int k = 0; k < 4; ++k) u[k] = hu[(p[k] & 0xFFFFF) * 64 + lane];
            #pragma unroll
            for (int k = 0; k < 4; ++k) v[k] = semb[(p[k] >> 20) * 64 + lane];
            #pragma unroll
            for (int k = 0; k < 4; ++k) {
                ax += fmaxf(__uint_as_float(u[k] << 16) + __uint_as_float(v[k] << 16), 0.f);
                ay += fmaxf(__uint_as_float(u[k] & 0xffff0000u) + __uint_as_float(v[k] & 0xffff0000u), 0.f);
            }
            j += 4;
        }

        for (; j < end; ++j) {
            const int p0 = __builtin_amdgcn_readfirstlane(epack[j]);
            const unsigned int u0 = hu[(p0 & 0xFFFFF) * 64 + lane];
            const unsigned int v0 = semb[(p0 >> 20) * 64 + lane];
            ax += fmaxf(__uint_as_float(u0 << 16) + __uint_as_float(v0 << 16), 0.f);
            ay += fmaxf(__uint_as_float(u0 & 0xffff0000u) + __uint_as_float(v0 & 0xffff0000u), 0.f);
        }

        float2 o; o.x = ax; o.y = ay;
        ((float2*)agg)[node * 64 + lane] = o;
    }
}

// ---------------- output projection ----------------
__global__ __launch_bounds__(256) void out_proj(
    const float* __restrict__ h, const float* __restrict__ Wout,
    const float* __restrict__ bout, float* __restrict__ out, int N)
{
    const int gt = blockIdx.x * 256 + threadIdx.x;
    const int r = gt >> 2;
    if (r >= N) return;
    const int q = gt & 3;

    const float* hr = &h[r * D + q * 32];
    const float* wr = &Wout[q * 32];
    float acc = 0.f;
    #pragma unroll
    for (int k = 0; k < 32; k += 4) {
        const float4 hv = ld4(hr + k);
        const float4 wv = ld4(wr + k);
        acc += hv.x * wv.x + hv.y * wv.y + hv.z * wv.z + hv.w * wv.w;
    }
    acc += __shfl_xor(acc, 1);
    acc += __shfl_xor(acc, 2);
    if (q == 0) out[r] = acc + bout[0];
}

extern "C" void kernel_launch(void* const* d_in, const int* in_sizes, int n_in,
                              void* d_out, int out_size, void* d_ws, size_t ws_size,
                              hipStream_t stream)
{
    const float* x     = (const float*)d_in[0];
    const int*   ei    = (const int*)  d_in[1];
    const int*   attr  = (const int*)  d_in[2];
    const float* emb   = (const float*)d_in[3];
    const float* Win   = (const float*)d_in[4];
    const float* b_in  = (const float*)d_in[5];
    const float* W1_0  = (const float*)d_in[6];
    const float* b1_0  = (const float*)d_in[7];
    const float* W2_0  = (const float*)d_in[8];
    const float* b2_0  = (const float*)d_in[9];
    const float* W1_1  = (const float*)d_in[10];
    const float* b1_1  = (const float*)d_in[11];
    const float* W2_1  = (const float*)d_in[12];
    const float* b2_1  = (const float*)d_in[13];
    const float* Wout  = (const float*)d_in[14];
    const float* b_out = (const float*)d_in[15];
    float* out = (float*)d_out;

    const int N = NN;
    const int E = in_sizes[2];
    const int* srcp = ei;
    const int* dstp = ei + E;
    const int nbins = (N + 255) >> 8;
    const int eblocks = (E + CHUNK - 1) / CHUNK;

    // persistent workspace
    unsigned short* h_hi = (unsigned short*)d_ws;        // N*D ushort
    unsigned short* h_lo = h_hi + (size_t)N * D;         // N*D ushort
    float* agg    = (float*)(h_lo + (size_t)N * D);      // N*D float
    int*   rowptr = (int*)(agg + (size_t)N * D);         // N
    int*   epack  = rowptr + N;                          // E
    unsigned short* wp = (unsigned short*)(epack + E);   // 5*2*D*D
    unsigned short* Whi[5], *Wlo[5];
    for (int i = 0; i < 5; ++i) {
        Whi[i] = wp + (size_t)i * 2 * D * D;
        Wlo[i] = Whi[i] + D * D;
    }
    unsigned int* embp = (unsigned int*)(wp + 5 * 2 * D * D);  // 100*64 uint
    // CSR-build scratch aliased into agg (dead until first aggregate)
    int2* binned    = (int2*)agg;                         // E
    int*  blkcnt    = (int*)(binned + E);                 // eblocks*BCSTRIDE
    int*  binTotal  = blkcnt + eblocks * BCSTRIDE;        // nbins
    int*  binStart  = binTotal + BCSTRIDE;                // nbins+1
    int*  binCursor = binStart + BCSTRIDE;                // nbins

    dim3 blk(256);
    const int fgrid = (N + 63) / 64;
    const int pgrid = (D * D + 255) / 256;

    // ---- prepack ----
    prepack_w<<<pgrid, blk, 0, stream>>>(Win,  Whi[0], Wlo[0]);
    prepack_w<<<pgrid, blk, 0, stream>>>(W1_0, Whi[1], Wlo[1]);
    prepack_w<<<pgrid, blk, 0, stream>>>(W2_0, Whi[2], Wlo[2]);
    prepack_w<<<pgrid, blk, 0, stream>>>(W1_1, Whi[3], Wlo[3]);
    prepack_w<<<pgrid, blk, 0, stream>>>(W2_1, Whi[4], Wlo[4]);
    prepack_emb<<<(100 * 64 + 255) / 256, blk, 0, stream>>>(emb, embp);

    // ---- binned CSR build ----
    hipMemsetAsync(binTotal, 0, BCSTRIDE * sizeof(int), stream);
    bin_count<<<eblocks, blk, 0, stream>>>(dstp, blkcnt, binTotal, E, nbins);
    bin_scan<<<1, 512, 0, stream>>>(binTotal, binStart, binCursor, nbins);
    bin_scatter<<<eblocks, blk, 0, stream>>>(srcp, dstp, attr, blkcnt, binCursor, binned, E, nbins);
    bin_build<<<nbins, blk, 0, stream>>>(binned, binStart, rowptr, epack, N);

    // ---- h = x @ Win + b_in  (write split h) ----
    gemm_in<<<fgrid, blk, 0, stream>>>(x, Whi[0], Wlo[0], b_in, h_hi, h_lo, N);

    // ---- layer 0 ----
    aggregate<<<AGG_BLOCKS, blk, 0, stream>>>(
        (const unsigned int*)h_hi, rowptr, epack, embp, agg, N);
    mlp_fused<false><<<fgrid, blk, 0, stream>>>(
        agg, h_hi, h_lo, Whi[1], Wlo[1], b1_0, Whi[2], Wlo[2], b2_0,
        h_hi, h_lo, nullptr, N);

    // ---- layer 1 (final h -> fp32 agg for out_proj) ----
    aggregate<<<AGG_BLOCKS, blk, 0, stream>>>(
        (const unsigned int*)h_hi, rowptr, epack, embp, agg, N);
    mlp_fused<true><<<fgrid, blk, 0, stream>>>(
        agg, h_hi, h_lo, Whi[3], Wlo[3], b1_1, Whi[4], Wlo[4], b2_1,
        nullptr, nullptr, agg, N);

    out_proj<<<(N * 4 + 255) / 256, blk, 0, stream>>>(agg, Wout, b_out, out, N);
}

// Round 15
// 500.095 us; speedup vs baseline: 1.0335x; 1.0335x over previous
//
#include <hip/hip_runtime.h>

#define NN 100000
#define D 128
#define CHUNK 4096
#define BCSTRIDE 392
#define AGG_BLOCKS 1024

typedef __attribute__((ext_vector_type(8))) short short8;
typedef __attribute__((ext_vector_type(8))) unsigned short ushort8;
typedef __attribute__((ext_vector_type(4))) float f32x4;

__device__ __forceinline__ float4 ld4(const float* p) { return *(const float4*)p; }

__device__ __forceinline__ unsigned short f2bf(float f) {
    unsigned int u = __float_as_uint(f);
    unsigned int r = u + 0x7fffu + ((u >> 16) & 1u);   // RNE
    return (unsigned short)(r >> 16);
}
__device__ __forceinline__ float bf2f(unsigned short h) {
    return __uint_as_float(((unsigned int)h) << 16);
}
// LDS swizzle: 128-uint row stride (32 KB tile -> 5 blocks/CU), rotate cols by
// (rloc>>2)*16 to break q-phase; chunk bases stay 8-aligned so b128 reads hold.
__device__ __forceinline__ int swz(int rloc, int c) {
    return rloc * 128 + ((c + ((rloc >> 2) << 4)) & 127);
}

// ---------------- fused setup: 5x W prepack + emb prepack + binTotal zero ----------------
__global__ __launch_bounds__(256) void setup_all(
    const float* __restrict__ W0, const float* __restrict__ W1,
    const float* __restrict__ W2, const float* __restrict__ W3,
    const float* __restrict__ W4, unsigned short* __restrict__ wp,
    const float* __restrict__ emb, unsigned int* __restrict__ embp,
    int* __restrict__ binTotal)
{
    const int T = blockIdx.x * 256 + threadIdx.x;
    if (T < 5 * D * D) {
        const int w = T / (D * D);
        const int t = T % (D * D);
        const float* W = (w == 0) ? W0 : (w == 1) ? W1 : (w == 2) ? W2 : (w == 3) ? W3 : W4;
        const int j  = t & 7;
        const int L  = (t >> 3) & 63;
        const int ks = (t >> 9) & 3;
        const int nt = t >> 11;
        const float v = W[(ks * 32 + (L >> 4) * 8 + j) * D + nt * 16 + (L & 15)];
        const unsigned short h = f2bf(v);
        unsigned short* hi = wp + (size_t)w * 2 * D * D;
        hi[t] = h;
        hi[D * D + t] = f2bf(v - bf2f(h));
    } else if (T < 5 * D * D + 6400) {
        const int i = T - 5 * D * D;
        embp[i] = (unsigned int)f2bf(emb[i * 2]) | ((unsigned int)f2bf(emb[i * 2 + 1]) << 16);
    } else if (T < 5 * D * D + 6400 + BCSTRIDE) {
        binTotal[T - 5 * D * D - 6400] = 0;
    }
}

// ---------------- input GEMM: h(split) = x @ Win + b_in ----------------
__global__ __launch_bounds__(256) void gemm_in(
    const float* __restrict__ A1,
    const unsigned short* __restrict__ Whi, const unsigned short* __restrict__ Wlo,
    const float* __restrict__ bias,
    unsigned short* __restrict__ out_hi, unsigned short* __restrict__ out_lo, int N)
{
    __shared__ unsigned int uT[64 * 128];   // 32 KB
    const int t  = threadIdx.x;
    const int wv = t >> 6;
    const int L  = t & 63;
    const int lr = L & 15;
    const int q  = L >> 4;
    const int rbase = wv * 16;
    const int row = blockIdx.x * 64 + rbase + lr;

    short8 ahi[4], alo[4];
    #pragma unroll
    for (int ks = 0; ks < 4; ++ks) {
        float v[8];
        if (row < N) {
            const int off = row * D + ks * 32 + q * 8;
            const float4 x0 = ld4(&A1[off]), x1 = ld4(&A1[off + 4]);
            v[0] = x0.x; v[1] = x0.y; v[2] = x0.z; v[3] = x0.w;
            v[4] = x1.x; v[5] = x1.y; v[6] = x1.z; v[7] = x1.w;
        } else {
            #pragma unroll
            for (int j = 0; j < 8; ++j) v[j] = 0.f;
        }
        #pragma unroll
        for (int j = 0; j < 8; ++j) {
            const unsigned short h = f2bf(v[j]);
            ahi[ks][j] = (short)h;
            alo[ks][j] = (short)f2bf(v[j] - bf2f(h));
        }
    }

    f32x4 acc[8];
    #pragma unroll
    for (int nt = 0; nt < 8; ++nt) acc[nt] = (f32x4){0.f, 0.f, 0.f, 0.f};

    #pragma unroll
    for (int ks = 0; ks < 4; ++ks)
        #pragma unroll
        for (int nt = 0; nt < 8; ++nt) {
            const int base = ((nt * 4 + ks) * 64 + L) * 8;
            const short8 bhi = *(const short8*)&Whi[base];
            const short8 blo = *(const short8*)&Wlo[base];
            acc[nt] = __builtin_amdgcn_mfma_f32_16x16x32_bf16(alo[ks], bhi, acc[nt], 0, 0, 0);
            acc[nt] = __builtin_amdgcn_mfma_f32_16x16x32_bf16(ahi[ks], blo, acc[nt], 0, 0, 0);
            acc[nt] = __builtin_amdgcn_mfma_f32_16x16x32_bf16(ahi[ks], bhi, acc[nt], 0, 0, 0);
        }

    #pragma unroll
    for (int nt = 0; nt < 8; ++nt) {
        const float b = bias[nt * 16 + lr];
        #pragma unroll
        for (int r = 0; r < 4; ++r) {
            const int rloc = rbase + q * 4 + r;
            uT[swz(rloc, nt * 16 + lr)] = __float_as_uint(acc[nt][r] + b);
        }
    }
    __syncthreads();
    if (row < N) {
        const int rl = rbase + lr;
        #pragma unroll
        for (int ks = 0; ks < 4; ++ks) {
            const unsigned int* p = &uT[swz(rl, ks * 32 + q * 8)];
            const int off = row * D + ks * 32 + q * 8;
            ushort8 oh, ol;
            #pragma unroll
            for (int j = 0; j < 8; ++j) {
                const float o = __uint_as_float(p[j]);
                const unsigned short h = f2bf(o);
                oh[j] = h;
                ol[j] = f2bf(o - bf2f(h));
            }
            *(ushort8*)&out_hi[off] = oh;
            *(ushort8*)&out_lo[off] = ol;
        }
    }
}

// ---------------- fused GINE MLP ----------------
template<bool LAST>
__global__ __launch_bounds__(256) void mlp_fused(
    const float* __restrict__ agg,
    const unsigned short* __restrict__ h_hi, const unsigned short* __restrict__ h_lo,
    const unsigned short* __restrict__ W1hi, const unsigned short* __restrict__ W1lo,
    const float* __restrict__ b1,
    const unsigned short* __restrict__ W2hi, const unsigned short* __restrict__ W2lo,
    const float* __restrict__ b2,
    unsigned short* __restrict__ out_hi, unsigned short* __restrict__ out_lo,
    float* __restrict__ out_f, int N)
{
    __shared__ unsigned int uT[64 * 128];   // 32 KB -> 5 blocks/CU
    const int t  = threadIdx.x;
    const int wv = t >> 6;
    const int L  = t & 63;
    const int lr = L & 15;
    const int q  = L >> 4;
    const int rbase = wv * 16;
    const int row = blockIdx.x * 64 + rbase + lr;

    ushort8 hh[4], ll[4];
    short8 ahi[4], alo[4];
    #pragma unroll
    for (int ks = 0; ks < 4; ++ks) {
        float v[8];
        if (row < N) {
            const int off = row * D + ks * 32 + q * 8;
            const float4 x0 = ld4(&agg[off]), x1 = ld4(&agg[off + 4]);
            hh[ks] = *(const ushort8*)&h_hi[off];
            ll[ks] = *(const ushort8*)&h_lo[off];
            v[0] = x0.x; v[1] = x0.y; v[2] = x0.z; v[3] = x0.w;
            v[4] = x1.x; v[5] = x1.y; v[6] = x1.z; v[7] = x1.w;
        } else {
            hh[ks] = (ushort8)0; ll[ks] = (ushort8)0;
            #pragma unroll
            for (int j = 0; j < 8; ++j) v[j] = 0.f;
        }
        #pragma unroll
        for (int j = 0; j < 8; ++j) {
            v[j] += bf2f(hh[ks][j]) + bf2f(ll[ks][j]);
            const unsigned short h = f2bf(v[j]);
            ahi[ks][j] = (short)h;
            alo[ks][j] = (short)f2bf(v[j] - bf2f(h));
        }
    }

    f32x4 acc[8];
    #pragma unroll
    for (int nt = 0; nt < 8; ++nt) acc[nt] = (f32x4){0.f, 0.f, 0.f, 0.f};

    #pragma unroll
    for (int ks = 0; ks < 4; ++ks)
        #pragma unroll
        for (int nt = 0; nt < 8; ++nt) {
            const int base = ((nt * 4 + ks) * 64 + L) * 8;
            const short8 bhi = *(const short8*)&W1hi[base];
            const short8 blo = *(const short8*)&W1lo[base];
            acc[nt] = __builtin_amdgcn_mfma_f32_16x16x32_bf16(alo[ks], bhi, acc[nt], 0, 0, 0);
            acc[nt] = __builtin_amdgcn_mfma_f32_16x16x32_bf16(ahi[ks], blo, acc[nt], 0, 0, 0);
            acc[nt] = __builtin_amdgcn_mfma_f32_16x16x32_bf16(ahi[ks], bhi, acc[nt], 0, 0, 0);
        }

    #pragma unroll
    for (int nt = 0; nt < 8; ++nt) {
        const float b = b1[nt * 16 + lr];
        #pragma unroll
        for (int r = 0; r < 4; ++r) {
            const int rloc = rbase + q * 4 + r;
            const float o = fmaxf(acc[nt][r] + b, 0.f);
            const unsigned int hi = f2bf(o);
            const unsigned int lo = f2bf(o - bf2f((unsigned short)hi));
            uT[swz(rloc, nt * 16 + lr)] = (hi << 16) | lo;
        }
    }
    __syncthreads();

    short8 uhi[4], ulo[4];
    {
        const int rl = rbase + lr;
        #pragma unroll
        for (int ks = 0; ks < 4; ++ks) {
            const unsigned int* p = &uT[swz(rl, ks * 32 + q * 8)];
            #pragma unroll
            for (int j = 0; j < 8; ++j) {
                const unsigned int v = p[j];
                uhi[ks][j] = (short)(v >> 16);
                ulo[ks][j] = (short)(v & 0xffffu);
            }
        }
    }

    f32x4 acc2[8];
    #pragma unroll
    for (int nt = 0; nt < 8; ++nt) acc2[nt] = (f32x4){0.f, 0.f, 0.f, 0.f};

    #pragma unroll
    for (int ks = 0; ks < 4; ++ks)
        #pragma unroll
        for (int nt = 0; nt < 8; ++nt) {
            const int base = ((nt * 4 + ks) * 64 + L) * 8;
            const short8 bhi = *(const short8*)&W2hi[base];
            const short8 blo = *(const short8*)&W2lo[base];
            acc2[nt] = __builtin_amdgcn_mfma_f32_16x16x32_bf16(ulo[ks], bhi, acc2[nt], 0, 0, 0);
            acc2[nt] = __builtin_amdgcn_mfma_f32_16x16x32_bf16(uhi[ks], blo, acc2[nt], 0, 0, 0);
            acc2[nt] = __builtin_amdgcn_mfma_f32_16x16x32_bf16(uhi[ks], bhi, acc2[nt], 0, 0, 0);
        }
    __syncthreads();

    #pragma unroll
    for (int nt = 0; nt < 8; ++nt) {
        const float b = b2[nt * 16 + lr];
        #pragma unroll
        for (int r = 0; r < 4; ++r) {
            const int rloc = rbase + q * 4 + r;
            uT[swz(rloc, nt * 16 + lr)] = __float_as_uint(acc2[nt][r] + b);
        }
    }
    __syncthreads();

    if (row < N) {
        const int rl = rbase + lr;
        #pragma unroll
        for (int ks = 0; ks < 4; ++ks) {
            const unsigned int* p = &uT[swz(rl, ks * 32 + q * 8)];
            const int off = row * D + ks * 32 + q * 8;
            float o[8];
            #pragma unroll
            for (int j = 0; j < 8; ++j)
                o[j] = fmaxf(__uint_as_float(p[j]) + bf2f(hh[ks][j]) + bf2f(ll[ks][j]), 0.f);
            if (LAST) {
                *(float4*)&out_f[off]     = make_float4(o[0], o[1], o[2], o[3]);
                *(float4*)&out_f[off + 4] = make_float4(o[4], o[5], o[6], o[7]);
            } else {
                ushort8 oh, ol;
                #pragma unroll
                for (int j = 0; j < 8; ++j) {
                    const unsigned short h = f2bf(o[j]);
                    oh[j] = h;
                    ol[j] = f2bf(o[j] - bf2f(h));
                }
                *(ushort8*)&out_hi[off] = oh;
                *(ushort8*)&out_lo[off] = ol;
            }
        }
    }
}

// ---------------- binned CSR build ----------------
__global__ __launch_bounds__(256) void bin_count(
    const int* __restrict__ dst, int* __restrict__ blkcnt,
    int* __restrict__ binTotal, int E, int nbins)
{
    __shared__ int hist[512];
    const int t = threadIdx.x;
    const int i = blockIdx.x;
    for (int k = t; k < nbins; k += 256) hist[k] = 0;
    __syncthreads();
    const int e0 = i * CHUNK;
    const int e1 = min(E, e0 + CHUNK);
    for (int e = e0 + t; e < e1; e += 256) atomicAdd(&hist[dst[e] >> 8], 1);
    __syncthreads();
    for (int k = t; k < nbins; k += 256) {
        const int c = hist[k];
        blkcnt[i * BCSTRIDE + k] = c;
        if (c) atomicAdd(&binTotal[k], c);
    }
}

__global__ __launch_bounds__(512) void bin_scan(
    const int* __restrict__ binTotal, int* __restrict__ binStart,
    int* __restrict__ binCursor, int nbins)
{
    __shared__ int s[512];
    const int t = threadIdx.x;
    const int v = (t < nbins) ? binTotal[t] : 0;
    s[t] = v;
    __syncthreads();
    for (int off = 1; off < 512; off <<= 1) {
        const int x = (t >= off) ? s[t - off] : 0;
        __syncthreads();
        s[t] += x;
        __syncthreads();
    }
    if (t < nbins) { binStart[t] = s[t] - v; binCursor[t] = s[t] - v; }
    if (t == 0)    binStart[nbins] = s[511];
}

__global__ __launch_bounds__(256) void bin_scatter(
    const int* __restrict__ src, const int* __restrict__ dst,
    const int* __restrict__ attr, const int* __restrict__ blkcnt,
    int* __restrict__ binCursor, int2* __restrict__ binned, int E, int nbins)
{
    __shared__ int cur[512];
    const int t = threadIdx.x;
    const int i = blockIdx.x;
    for (int k = t; k < nbins; k += 256) {
        const int c = blkcnt[i * BCSTRIDE + k];
        if (c) cur[k] = atomicAdd(&binCursor[k], c);
    }
    __syncthreads();
    const int e0 = i * CHUNK;
    const int e1 = min(E, e0 + CHUNK);
    for (int e = e0 + t; e < e1; e += 256) {
        const int d = dst[e];
        const int p = atomicAdd(&cur[d >> 8], 1);
        binned[p] = make_int2(src[e] | (attr[e] << 20), d);
    }
}

__global__ __launch_bounds__(256) void bin_build(
    const int2* __restrict__ binned, const int* __restrict__ binStart,
    int* __restrict__ rowptr, int* __restrict__ epack, int N)
{
    __shared__ int hist[256];
    __shared__ int scn[256];
    __shared__ int curn[256];
    const int t = threadIdx.x;
    const int b = blockIdx.x;
    hist[t] = 0;
    __syncthreads();
    const int ebeg = binStart[b];
    const int eend = binStart[b + 1];
    for (int e = ebeg + t; e < eend; e += 256) atomicAdd(&hist[binned[e].y & 255], 1);
    __syncthreads();
    scn[t] = hist[t];
    __syncthreads();
    for (int off = 1; off < 256; off <<= 1) {
        const int x = (t >= off) ? scn[t - off] : 0;
        __syncthreads();
        scn[t] += x;
        __syncthreads();
    }
    const int node = b * 256 + t;
    if (node < N) rowptr[node] = ebeg + scn[t];
    curn[t] = ebeg + scn[t] - hist[t];
    __syncthreads();
    for (int e = ebeg + t; e < eend; e += 256) {
        const int2 v = binned[e];
        const int p = atomicAdd(&curn[v.y & 255], 1);
        epack[p] = v.x;
    }
}

// ---------------- CSR aggregate: 512-thr blocks (8 waves share semb) ----------------
__global__ __launch_bounds__(512) void aggregate(
    const unsigned int* __restrict__ hu,
    const int* __restrict__ rowptr, const int* __restrict__ epack,
    const unsigned int* __restrict__ embp, float* __restrict__ agg, int N)
{
    __shared__ unsigned int semb[100 * 64];   // 25.6 KB packed bf16 emb table
    const int t = threadIdx.x;
    for (int i = t; i < 100 * 64; i += 512) semb[i] = embp[i];
    __syncthreads();

    const int wv   = t >> 6;    // 0..7
    const int lane = t & 63;

    for (int node = blockIdx.x * 8 + wv; node < N; node += AGG_BLOCKS * 8) {
        int start = (node == 0) ? 0 : rowptr[node - 1];
        int end   = rowptr[node];
        start = __builtin_amdgcn_readfirstlane(start);
        end   = __builtin_amdgcn_readfirstlane(end);

        float ax = 0.f, ay = 0.f;
        int j = start;

        for (; j < end && (j & 3); ++j) {
            const int p0 = __builtin_amdgcn_readfirstlane(epack[j]);
            const unsigned int u0 = hu[(p0 & 0xFFFFF) * 64 + lane];
            const unsigned int v0 = semb[(p0 >> 20) * 64 + lane];
            ax += fmaxf(__uint_as_float(u0 << 16) + __uint_as_float(v0 << 16), 0.f);
            ay += fmaxf(__uint_as_float(u0 & 0xffff0000u) + __uint_as_float(v0 & 0xffff0000u), 0.f);
        }

        for (; j + 7 < end; j += 8) {
            const int4 pk0 = *(const int4*)&epack[j];
            const int4 pk1 = *(const int4*)&epack[j + 4];
            int p[8];
            p[0] = __builtin_amdgcn_readfirstlane(pk0.x);
            p[1] = __builtin_amdgcn_readfirstlane(pk0.y);
            p[2] = __builtin_amdgcn_readfirstlane(pk0.z);
            p[3] = __builtin_amdgcn_readfirstlane(pk0.w);
            p[4] = __builtin_amdgcn_readfirstlane(pk1.x);
            p[5] = __builtin_amdgcn_readfirstlane(pk1.y);
            p[6] = __builtin_amdgcn_readfirstlane(pk1.z);
            p[7] = __builtin_amdgcn_readfirstlane(pk1.w);
            unsigned int u[8], v[8];
            #pragma unroll
            for (int k = 0; k < 8; ++k) u[k] = hu[(p[k] & 0xFFFFF) * 64 + lane];
            #pragma unroll
            for (int k = 0; k < 8; ++k) v[k] = semb[(p[k] >> 20) * 64 + lane];
            #pragma unroll
            for (int k = 0; k < 8; ++k) {
                ax += fmaxf(__uint_as_float(u[k] << 16) + __uint_as_float(v[k] << 16), 0.f);
                ay += fmaxf(__uint_as_float(u[k] & 0xffff0000u) + __uint_as_float(v[k] & 0xffff0000u), 0.f);
            }
        }

        if (j + 3 < end) {
            const int4 pk0 = *(const int4*)&epack[j];
            int p[4];
            p[0] = __builtin_amdgcn_readfirstlane(pk0.x);
            p[1] = __builtin_amdgcn_readfirstlane(pk0.y);
            p[2] = __builtin_amdgcn_readfirstlane(pk0.z);
            p[3] = __builtin_amdgcn_readfirstlane(pk0.w);
            unsigned int u[4], v[4];
            #pragma unroll
            for (int k = 0; k < 4; ++k) u[k] = hu[(p[k] & 0xFFFFF) * 64 + lane];
            #pragma unroll
            for (int k = 0; k < 4; ++k) v[k] = semb[(p[k] >> 20) * 64 + lane];
            #pragma unroll
            for (int k = 0; k < 4; ++k) {
                ax += fmaxf(__uint_as_float(u[k] << 16) + __uint_as_float(v[k] << 16), 0.f);
                ay += fmaxf(__uint_as_float(u[k] & 0xffff0000u) + __uint_as_float(v[k] & 0xffff0000u), 0.f);
            }
            j += 4;
        }

        for (; j < end; ++j) {
            const int p0 = __builtin_amdgcn_readfirstlane(epack[j]);
            const unsigned int u0 = hu[(p0 & 0xFFFFF) * 64 + lane];
            const unsigned int v0 = semb[(p0 >> 20) * 64 + lane];
            ax += fmaxf(__uint_as_float(u0 << 16) + __uint_as_float(v0 << 16), 0.f);
            ay += fmaxf(__uint_as_float(u0 & 0xffff0000u) + __uint_as_float(v0 & 0xffff0000u), 0.f);
        }

        float2 o; o.x = ax; o.y = ay;
        ((float2*)agg)[node * 64 + lane] = o;
    }
}

// ---------------- output projection ----------------
__global__ __launch_bounds__(256) void out_proj(
    const float* __restrict__ h, const float* __restrict__ Wout,
    const float* __restrict__ bout, float* __restrict__ out, int N)
{
    const int gt = blockIdx.x * 256 + threadIdx.x;
    const int r = gt >> 2;
    if (r >= N) return;
    const int q = gt & 3;

    const float* hr = &h[r * D + q * 32];
    const float* wr = &Wout[q * 32];
    float acc = 0.f;
    #pragma unroll
    for (int k = 0; k < 32; k += 4) {
        const float4 hv = ld4(hr + k);
        const float4 wv = ld4(wr + k);
        acc += hv.x * wv.x + hv.y * wv.y + hv.z * wv.z + hv.w * wv.w;
    }
    acc += __shfl_xor(acc, 1);
    acc += __shfl_xor(acc, 2);
    if (q == 0) out[r] = acc + bout[0];
}

extern "C" void kernel_launch(void* const* d_in, const int* in_sizes, int n_in,
                              void* d_out, int out_size, void* d_ws, size_t ws_size,
                              hipStream_t stream)
{
    const float* x     = (const float*)d_in[0];
    const int*   ei    = (const int*)  d_in[1];
    const int*   attr  = (const int*)  d_in[2];
    const float* emb   = (const float*)d_in[3];
    const float* Win   = (const float*)d_in[4];
    const float* b_in  = (const float*)d_in[5];
    const float* W1_0  = (const float*)d_in[6];
    const float* b1_0  = (const float*)d_in[7];
    const float* W2_0  = (const float*)d_in[8];
    const float* b2_0  = (const float*)d_in[9];
    const float* W1_1  = (const float*)d_in[10];
    const float* b1_1  = (const float*)d_in[11];
    const float* W2_1  = (const float*)d_in[12];
    const float* b2_1  = (const float*)d_in[13];
    const float* Wout  = (const float*)d_in[14];
    const float* b_out = (const float*)d_in[15];
    float* out = (float*)d_out;

    const int N = NN;
    const int E = in_sizes[2];
    const int* srcp = ei;
    const int* dstp = ei + E;
    const int nbins = (N + 255) >> 8;
    const int eblocks = (E + CHUNK - 1) / CHUNK;

    // persistent workspace
    unsigned short* h_hi = (unsigned short*)d_ws;        // N*D ushort
    unsigned short* h_lo = h_hi + (size_t)N * D;         // N*D ushort
    float* agg    = (float*)(h_lo + (size_t)N * D);      // N*D float
    int*   rowptr = (int*)(agg + (size_t)N * D);         // N
    int*   epack  = rowptr + N;                          // E
    unsigned short* wp = (unsigned short*)(epack + E);   // 5*2*D*D
    unsigned short* Whi[5], *Wlo[5];
    for (int i = 0; i < 5; ++i) {
        Whi[i] = wp + (size_t)i * 2 * D * D;
        Wlo[i] = Whi[i] + D * D;
    }
    unsigned int* embp = (unsigned int*)(wp + 5 * 2 * D * D);  // 100*64 uint
    // CSR-build scratch aliased into agg (dead until first aggregate)
    int2* binned    = (int2*)agg;                         // E
    int*  blkcnt    = (int*)(binned + E);                 // eblocks*BCSTRIDE
    int*  binTotal  = blkcnt + eblocks * BCSTRIDE;        // nbins
    int*  binStart  = binTotal + BCSTRIDE;                // nbins+1
    int*  binCursor = binStart + BCSTRIDE;                // nbins

    dim3 blk(256);
    const int fgrid = (N + 63) / 64;
    const int sgrid = (5 * D * D + 6400 + BCSTRIDE + 255) / 256;

    // ---- fused setup: W/emb prepack + binTotal zero ----
    setup_all<<<sgrid, blk, 0, stream>>>(Win, W1_0, W2_0, W1_1, W2_1, wp, emb, embp, binTotal);

    // ---- binned CSR build ----
    bin_count<<<eblocks, blk, 0, stream>>>(dstp, blkcnt, binTotal, E, nbins);
    bin_scan<<<1, 512, 0, stream>>>(binTotal, binStart, binCursor, nbins);
    bin_scatter<<<eblocks, blk, 0, stream>>>(srcp, dstp, attr, blkcnt, binCursor, binned, E, nbins);
    bin_build<<<nbins, blk, 0, stream>>>(binned, binStart, rowptr, epack, N);

    // ---- h = x @ Win + b_in  (write split h) ----
    gemm_in<<<fgrid, blk, 0, stream>>>(x, Whi[0], Wlo[0], b_in, h_hi, h_lo, N);

    // ---- layer 0 ----
    aggregate<<<AGG_BLOCKS, dim3(512), 0, stream>>>(
        (const unsigned int*)h_hi, rowptr, epack, embp, agg, N);
    mlp_fused<false><<<fgrid, blk, 0, stream>>>(
        agg, h_hi, h_lo, Whi[1], Wlo[1], b1_0, Whi[2], Wlo[2], b2_0,
        h_hi, h_lo, nullptr, N);

    // ---- layer 1 (final h -> fp32 agg for out_proj) ----
    aggregate<<<AGG_BLOCKS, dim3(512), 0, stream>>>(
        (const unsigned int*)h_hi, rowptr, epack, embp, agg, N);
    mlp_fused<true><<<fgrid, blk, 0, stream>>>(
        agg, h_hi, h_lo, Whi[3], Wlo[3], b1_1, Whi[4], Wlo[4], b2_1,
        nullptr, nullptr, agg, N);

    out_proj<<<(N * 4 + 255) / 256, blk, 0, stream>>>(agg, Wout, b_out, out, N);
}